// Round 11
// baseline (220.398 us; speedup 1.0000x reference)
//
#include <hip/hip_runtime.h>
#include <hip/hip_bf16.h>
#include <hip/hip_fp16.h>

typedef __attribute__((ext_vector_type(8))) short bf16x8;   // 8 bf16 = 4 VGPRs
typedef __attribute__((ext_vector_type(4))) float f32x4;
typedef unsigned short u16;
typedef unsigned int uint;
typedef unsigned long long u64;

#define Bb 2
#define Tt 2048
#define Dd 1024
#define Hh 16

#define EXP2F(x) __builtin_amdgcn_exp2f(x)

__device__ inline u16 f2bf(float f) {
    union { float f; uint u; } v; v.f = f;
    uint r = v.u + 0x7fffu + ((v.u >> 16) & 1u);   // RNE
    return (u16)(r >> 16);
}
__device__ inline uint fbits(float f) { union { float f; uint u; } v; v.f = f; return v.u; }
__device__ inline u16 f2h(float f) { return __half_as_ushort(__float2half(f)); }
__device__ inline float h2f(u16 u) { return __half2float(__ushort_as_half(u)); }

// async global->LDS, 16B per lane; dest wave-uniform base + lane*16.
__device__ inline void glds16(const u16* g, u16* l) {
    __builtin_amdgcn_global_load_lds(
        (const __attribute__((address_space(1))) void*)g,
        (__attribute__((address_space(3))) void*)l,
        16, 0, 0);
}

// ---------------------------------------------------------------------------
// prep: fused {fp32->bf16 cvt of x} + {transpose_cvt Wqkv} + {transpose_cvt
// Wout} + {zero split-K counters} in one dispatch. Role by blockIdx.x:
//   [0,2048)        cvt 8 elems/thread of x -> xb
//   [2048,2816)     Wqkv [1024][3072] -> WqT [3072][1024]
//   [2816,3072)     Wout [1024][1024] -> WoT [1024][1024]
//   3072            zero ALL 512 attn split-K arrival counters
// ---------------------------------------------------------------------------
__global__ __launch_bounds__(256) void prep(
    const float* __restrict__ x, u16* __restrict__ xb,
    const float* __restrict__ Wqkv, u16* __restrict__ WqT,
    const float* __restrict__ Wout, u16* __restrict__ WoT,
    int* __restrict__ cnt)
{
    __shared__ float tile[64][65];
    const int bid = blockIdx.x;
    const int tid = threadIdx.x;

    if (bid == 3072) {           // counter-zero role: 256 threads x 2 entries
        cnt[tid]       = 0;
        cnt[tid + 256] = 0;
        return;
    }
    if (bid < 2048) {            // elementwise cvt role
        const size_t i = ((size_t)bid * 256 + tid) * 8;
        const float4 a = *(const float4*)&x[i];
        const float4 b = *(const float4*)&x[i + 4];
        uint4 o;
        o.x = (uint)f2bf(a.x) | ((uint)f2bf(a.y) << 16);
        o.y = (uint)f2bf(a.z) | ((uint)f2bf(a.w) << 16);
        o.z = (uint)f2bf(b.x) | ((uint)f2bf(b.y) << 16);
        o.w = (uint)f2bf(b.z) | ((uint)f2bf(b.w) << 16);
        *(uint4*)&xb[i] = o;
        return;
    }

    const float* W; u16* Wt; int N, bx, by;
    const int K = 1024;
    if (bid < 2048 + 768) {
        const int r = bid - 2048;
        W = Wqkv; Wt = WqT; N = 3072; bx = r % 48; by = r / 48;
    } else {
        const int r = bid - 2816;
        W = Wout; Wt = WoT; N = 1024; bx = r & 15; by = r >> 4;
    }
    const int k0 = by * 64, n0 = bx * 64;
    const int tr = tid >> 4;
    const int tc = (tid & 15) * 4;

    #pragma unroll
    for (int i = 0; i < 4; ++i) {
        const float4 v = *(const float4*)&W[(size_t)(k0 + tr + i * 16) * N + n0 + tc];
        tile[tr + i * 16][tc + 0] = v.x;
        tile[tr + i * 16][tc + 1] = v.y;
        tile[tr + i * 16][tc + 2] = v.z;
        tile[tr + i * 16][tc + 3] = v.w;
    }
    __syncthreads();
    #pragma unroll
    for (int i = 0; i < 4; ++i) {
        ushort4 o;
        o.x = f2bf(tile[tc + 0][tr + i * 16]);
        o.y = f2bf(tile[tc + 1][tr + i * 16]);
        o.z = f2bf(tile[tc + 2][tr + i * 16]);
        o.w = f2bf(tile[tc + 3][tr + i * 16]);
        *(ushort4*)&Wt[(size_t)(n0 + tr + i * 16) * K + k0 + tc] = o;
    }
}

// ---------------------------------------------------------------------------
// C = A @ Bt^T + bias, bf16 MFMA. m97-style glds staging + double-buffered
// prefetch (one barrier per K-iter). 2x16 KB LDS. XOR source swizzle,
// conflict-free frag reads. VERIFIED 45 µs structure.
// MODE 0: fp32 out, row-major stride N (gemm2).
// MODE 1: qkv proj: cols <2048 -> bf16 qkvb stride 2048 (Q,K);
//         cols >=2048 -> V scattered transposed into vg[b][h][d][T].
// ---------------------------------------------------------------------------
template <int MODE>
__global__ __launch_bounds__(256) void gemm_bt(
    const u16* __restrict__ A, const u16* __restrict__ Bt,
    const float* __restrict__ bias, void* __restrict__ C,
    u16* __restrict__ vg, int M, int N, int K)
{
    __shared__ u16 As[2][128 * 32];
    __shared__ u16 Bs[2][128 * 32];

    const int tid  = threadIdx.x;
    const int lane = tid & 63;
    const int w    = tid >> 6;
    const int wm   = w >> 1, wn = w & 1;
    const int quad = lane >> 4;
    const int m16  = lane & 15;
    const int row0 = blockIdx.y * 128;
    const int col0 = blockIdx.x * 128;

    f32x4 acc[4][4];
    #pragma unroll
    for (int i = 0; i < 4; ++i)
        #pragma unroll
        for (int j = 0; j < 4; ++j) acc[i][j] = (f32x4){0.f, 0.f, 0.f, 0.f};

    const int sr  = tid >> 2, sqs = tid & 3;
    const int sq  = sqs ^ ((sr >> 1) & 3);
    const int ldsw = w * 512;
    const int slot = quad ^ ((m16 >> 1) & 3);

    const int nIter = K >> 5;

    // prologue: stage iter 0 into buf 0
    glds16(&A [(size_t)(row0 + sr) * K + sq * 8],       &As[0][ldsw]);
    glds16(&A [(size_t)(row0 + sr + 64) * K + sq * 8],  &As[0][2048 + ldsw]);
    glds16(&Bt[(size_t)(col0 + sr) * K + sq * 8],       &Bs[0][ldsw]);
    glds16(&Bt[(size_t)(col0 + sr + 64) * K + sq * 8],  &Bs[0][2048 + ldsw]);

    for (int it = 0; it < nIter; ++it) {
        const int cb = it & 1;
        __syncthreads();   // drains glds(iter it); all waves done reading buf cb^1

        if (it + 1 < nIter) {   // prefetch next k-slab into the other buffer
            const int ko = (it + 1) << 5;
            const int nb = cb ^ 1;
            glds16(&A [(size_t)(row0 + sr) * K + ko + sq * 8],       &As[nb][ldsw]);
            glds16(&A [(size_t)(row0 + sr + 64) * K + ko + sq * 8],  &As[nb][2048 + ldsw]);
            glds16(&Bt[(size_t)(col0 + sr) * K + ko + sq * 8],       &Bs[nb][ldsw]);
            glds16(&Bt[(size_t)(col0 + sr + 64) * K + ko + sq * 8],  &Bs[nb][2048 + ldsw]);
        }

        bf16x8 af[4], bfr[4];
        #pragma unroll
        for (int mt = 0; mt < 4; ++mt)
            af[mt] = *(const bf16x8*)&As[cb][(wm * 64 + mt * 16 + m16) * 32 + slot * 8];
        #pragma unroll
        for (int nt = 0; nt < 4; ++nt)
            bfr[nt] = *(const bf16x8*)&Bs[cb][(wn * 64 + nt * 16 + m16) * 32 + slot * 8];
        #pragma unroll
        for (int mt = 0; mt < 4; ++mt)
            #pragma unroll
            for (int nt = 0; nt < 4; ++nt)
                acc[mt][nt] = __builtin_amdgcn_mfma_f32_16x16x32_bf16(
                    af[mt], bfr[nt], acc[mt][nt], 0, 0, 0);
    }

    #pragma unroll
    for (int mt = 0; mt < 4; ++mt) {
        #pragma unroll
        for (int nt = 0; nt < 4; ++nt) {
            const int row = row0 + wm * 64 + mt * 16 + quad * 4;
            const int col = col0 + wn * 64 + nt * 16 + m16;
            const float bv = bias[col];
            #pragma unroll
            for (int r = 0; r < 4; ++r) {
                const float v = acc[mt][nt][r] + bv;
                if (MODE == 0) {
                    ((float*)C)[(size_t)(row + r) * N + col] = v;
                } else {
                    if (col0 < 2048) {   // Q,K region (block never straddles)
                        ((u16*)C)[(size_t)(row + r) * 2048 + col] = f2bf(v);
                    } else {             // V: write transposed into vg[b][h][d][T]
                        const int hcol = col - 2048;
                        const int hh = hcol >> 6, dd = hcol & 63;
                        const int bb = (row + r) >> 11, tt = (row + r) & 2047;
                        vg[((size_t)(bb * Hh + hh) * 64 + dd) * Tt + tt] = f2bf(v);
                    }
                }
            }
        }
    }
}

// ---------------------------------------------------------------------------
// Flash causal attention v10: R19 removes the Pt LDS bounce — P is
// redistributed IN-REGISTER via cross-quad ds_bpermute (__shfl).
// Derivation: after S^T=K·Q^T, lane(quad,m16) holds P[q=m16][k=mt*16+quad*4+r].
// PV B-frag needs P[q=m16][k=ks*32+quad*8+j]: j=0..3 from lane(2*(quad&1),m16)
// regs of mt=2ks+(quad>>1); j=4..7 from lane(2*(quad&1)+1,m16). Fixed
// permutation -> 32 shfl + 8 cndmask replace 8 ds_write + 4 ds_read_b128 +
// lgkm round-trip; frees 18 KB LDS -> 33 KB -> 4 blocks/CU (grid = exactly
// 4/CU). P bits identical (same truncation pack) -> absmax unchanged.
// KV dbuf (R18) + T5 setprio + sc1 fused combine (R15) retained.
// ---------------------------------------------------------------------------
__global__ __launch_bounds__(256, 4) void attn_split(
    const u16* __restrict__ qkvb, const u16* __restrict__ vglob,
    u16* __restrict__ wsO, float* __restrict__ wsL,
    u16* __restrict__ attb, int* __restrict__ cnt)
{
    const int hb  = blockIdx.x;
    const int h   = hb & 15, b = hb >> 4;
    const int qt  = 15 - (blockIdx.y >> 1);   // heavy-first
    const int half = blockIdx.y & 1;
    const int tid = threadIdx.x;
    const int lane = tid & 63, w = tid >> 6;
    const int quad = lane >> 4, m16 = lane & 15;

    __shared__ u16 KV[2][2][64 * 64];    // [buf][K=0/Vt=1], 32 KB
    __shared__ int sflag;

    const int q0 = qt * 128;
    const size_t qkbase = (size_t)(b * Tt) * 2048;
    const size_t vbase  = (size_t)((b * Hh + h) * 64) * Tt;

    const int sr8 = tid >> 3;                // 0..31
    const int sq8 = (tid & 7) ^ (sr8 & 7);
    const int ldsw = w * 512;
    const int slot = quad ^ (m16 & 7);       // ks=0 read slot; ks=1 -> ^4

    // P-shuffle source lanes (fixed permutation, hoisted):
    const int srcA = ((quad & 1) << 5) + m16;   // lane of quad 2*(quad&1)
    const int srcB = srcA + 16;                 // lane of quad 2*(quad&1)+1

    // Q^T B-frags, loop-invariant, from global:
    bf16x8 qb[2][2];
    #pragma unroll
    for (int nt = 0; nt < 2; ++nt)
        #pragma unroll
        for (int ks = 0; ks < 2; ++ks)
            qb[nt][ks] = *(const bf16x8*)&qkvb[
                qkbase + (size_t)(q0 + w * 32 + nt * 16 + m16) * 2048
                + h * 64 + ks * 32 + quad * 8];

    f32x4 o[4][2];
    #pragma unroll
    for (int ct = 0; ct < 4; ++ct)
        #pragma unroll
        for (int nt = 0; nt < 2; ++nt) o[ct][nt] = (f32x4){0.f, 0.f, 0.f, 0.f};
    float ls[2] = {0.f, 0.f};
    const float sc2 = 0.125f * 1.4426950408889634f;   // scale*log2(e)

    #define STAGE_KV(K0, BUF) do {                                             \
        _Pragma("unroll")                                                      \
        for (int j_ = 0; j_ < 2; ++j_) {                                       \
            const int row_ = j_ * 32 + sr8;                                    \
            glds16(&qkvb[qkbase + (size_t)((K0) + row_) * 2048 + 1024          \
                         + h * 64 + sq8 * 8],                                  \
                   &KV[BUF][0][j_ * 2048 + ldsw]);                             \
            glds16(&vglob[vbase + (size_t)row_ * Tt + (K0) + sq8 * 8],         \
                   &KV[BUF][1][j_ * 2048 + ldsw]);                             \
        }                                                                      \
    } while (0)

    const int ntiles = 2 * qt + 2;
    // prologue: stage first tile into buf 0
    STAGE_KV(half * 64, 0);

    int it = 0;
    for (int kt = half; kt < ntiles; kt += 2, ++it) {
        const int k0 = kt * 64;
        const int cb = it & 1;
        __syncthreads();   // vmcnt(0)+barrier: buf cb visible; reads of cb^1 retired

        if (kt + 2 < ntiles)            // prefetch tile t+2 into the other buffer
            STAGE_KV((kt + 2) * 64, cb ^ 1);

        if (k0 <= q0 + w * 32 + 31) {    // wave-uniform visibility
            const u16* Ks = KV[cb][0];
            const u16* Vt = KV[cb][1];

            // S^T = K · Q^T
            bf16x8 ak[4][2];
            #pragma unroll
            for (int mt = 0; mt < 4; ++mt) {
                const int ro = (mt * 16 + m16) * 64;
                ak[mt][0] = *(const bf16x8*)&Ks[ro + slot * 8];
                ak[mt][1] = *(const bf16x8*)&Ks[ro + (slot ^ 4) * 8];
            }
            f32x4 s[4][2];
            __builtin_amdgcn_s_setprio(1);
            #pragma unroll
            for (int mt = 0; mt < 4; ++mt)
                #pragma unroll
                for (int nt = 0; nt < 2; ++nt) {
                    f32x4 a = (f32x4){0.f, 0.f, 0.f, 0.f};
                    a = __builtin_amdgcn_mfma_f32_16x16x32_bf16(ak[mt][0], qb[nt][0], a, 0, 0, 0);
                    a = __builtin_amdgcn_mfma_f32_16x16x32_bf16(ak[mt][1], qb[nt][1], a, 0, 0, 0);
                    s[mt][nt] = a;
                }
            __builtin_amdgcn_s_setprio(0);

            // p = exp2(s*sc2 - 8), causal mask -> 0; accumulate l per-lane.
            // Pack to bf16 pairs IN REGISTERS (same truncation bits as before).
            const int qi0 = q0 + w * 32 + m16;
            const bool diag = (k0 + 63 > q0 + w * 32);
            uint pkk[2][4][2];   // [nt][mt][u32 pair] — all indices static
            #pragma unroll
            for (int mt = 0; mt < 4; ++mt)
                #pragma unroll
                for (int nt = 0; nt < 2; ++nt) {
                    float p[4];
                    const int kb = k0 + mt * 16 + quad * 4;
                    #pragma unroll
                    for (int r = 0; r < 4; ++r) {
                        float t = __builtin_fmaf(s[mt][nt][r], sc2, -8.0f);
                        if (diag) t = (kb + r <= qi0 + nt * 16) ? t : -1000.0f;
                        p[r] = EXP2F(t);
                    }
                    ls[nt] += (p[0] + p[1]) + (p[2] + p[3]);
                    pkk[nt][mt][0] = (fbits(p[0]) >> 16) | (fbits(p[1]) & 0xffff0000u);
                    pkk[nt][mt][1] = (fbits(p[2]) >> 16) | (fbits(p[3]) & 0xffff0000u);
                }

            // Redistribute P cross-quad: pb[nt][ks] u32[0..1] from srcA
            // (regs of mt=2ks+(quad>>1)), u32[2..3] from srcB.
            bf16x8 pb[2][2];
            #pragma unroll
            for (int nt = 0; nt < 2; ++nt) {
                uint a0[4], a1[4], b0[4], b1[4];
                #pragma unroll
                for (int mt = 0; mt < 4; ++mt) {
                    a0[mt] = (uint)__shfl((int)pkk[nt][mt][0], srcA);
                    a1[mt] = (uint)__shfl((int)pkk[nt][mt][1], srcA);
                    b0[mt] = (uint)__shfl((int)pkk[nt][mt][0], srcB);
                    b1[mt] = (uint)__shfl((int)pkk[nt][mt][1], srcB);
                }
                #pragma unroll
                for (int ks = 0; ks < 2; ++ks) {
                    const bool hi = (quad & 2) != 0;   // quad>>1
                    union { uint4 u; bf16x8 v; } cvt;
                    cvt.u.x = hi ? a0[2 * ks + 1] : a0[2 * ks];
                    cvt.u.y = hi ? a1[2 * ks + 1] : a1[2 * ks];
                    cvt.u.z = hi ? b0[2 * ks + 1] : b0[2 * ks];
                    cvt.u.w = hi ? b1[2 * ks + 1] : b1[2 * ks];
                    pb[nt][ks] = cvt.v;
                }
            }

            // O^T += V^T · P^T
            bf16x8 av[4][2];
            #pragma unroll
            for (int ct = 0; ct < 4; ++ct) {
                const int ro = (ct * 16 + m16) * 64;
                av[ct][0] = *(const bf16x8*)&Vt[ro + slot * 8];
                av[ct][1] = *(const bf16x8*)&Vt[ro + (slot ^ 4) * 8];
            }
            __builtin_amdgcn_s_setprio(1);
            #pragma unroll
            for (int ct = 0; ct < 4; ++ct)
                #pragma unroll
                for (int nt = 0; nt < 2; ++nt) {
                    o[ct][nt] = __builtin_amdgcn_mfma_f32_16x16x32_bf16(av[ct][0], pb[nt][0], o[ct][nt], 0, 0, 0);
                    o[ct][nt] = __builtin_amdgcn_mfma_f32_16x16x32_bf16(av[ct][1], pb[nt][1], o[ct][nt], 0, 0, 0);
                }
            __builtin_amdgcn_s_setprio(0);
        }
    }
    #undef STAGE_KV

    // epilogue: reduce l across quads (all lanes end with the full sum).
    #pragma unroll
    for (int nt = 0; nt < 2; ++nt) {
        ls[nt] += __shfl_xor(ls[nt], 16);
        ls[nt] += __shfl_xor(ls[nt], 32);
    }
    const int qrow = b * Tt + q0 + w * 32 + m16;
    if (quad == 0) {
        __hip_atomic_store(&wsL[(half * Hh + h) * 4096 + qrow], ls[0],
                           __ATOMIC_RELAXED, __HIP_MEMORY_SCOPE_AGENT);
        __hip_atomic_store(&wsL[(half * Hh + h) * 4096 + qrow + 16], ls[1],
                           __ATOMIC_RELAXED, __HIP_MEMORY_SCOPE_AGENT);
    }
    // own fp16 partial: agent-scope (sc1) stores, device-visible at vmcnt retire
    ushort4 own[4][2];
    #pragma unroll
    for (int ct = 0; ct < 4; ++ct)
        #pragma unroll
        for (int nt = 0; nt < 2; ++nt) {
            ushort4 pk;
            pk.x = f2h(o[ct][nt][0]);
            pk.y = f2h(o[ct][nt][1]);
            pk.z = f2h(o[ct][nt][2]);
            pk.w = f2h(o[ct][nt][3]);
            own[ct][nt] = pk;
            union { ushort4 s; u64 u; } cv; cv.s = pk;
            __hip_atomic_store(
                (u64*)&wsO[((size_t)(half * 4096 + qrow + nt * 16)) * 1024
                           + h * 64 + ct * 16 + quad * 4],
                cv.u, __ATOMIC_RELAXED, __HIP_MEMORY_SCOPE_AGENT);
        }

    // last-arrival combine: syncthreads (vmcnt0 -> all sc1 stores device-
    // visible) -> ticket -> combiner reads partner with agent loads.
    __syncthreads();
    if (tid == 0) sflag = atomicAdd(&cnt[hb * 16 + qt], 1);
    __syncthreads();
    if (sflag == 1) {
        const int oh = half ^ 1;
        const float lo0 = __hip_atomic_load(&wsL[(oh * Hh + h) * 4096 + qrow],
                                            __ATOMIC_RELAXED, __HIP_MEMORY_SCOPE_AGENT);
        const float lo1 = __hip_atomic_load(&wsL[(oh * Hh + h) * 4096 + qrow + 16],
                                            __ATOMIC_RELAXED, __HIP_MEMORY_SCOPE_AGENT);
        const float il[2] = { 1.0f / (ls[0] + lo0), 1.0f / (ls[1] + lo1) };
        #pragma unroll
        for (int ct = 0; ct < 4; ++ct)
            #pragma unroll
            for (int nt = 0; nt < 2; ++nt) {
                const u64 pbits = __hip_atomic_load(
                    (const u64*)&wsO[((size_t)(oh * 4096 + qrow + nt * 16)) * 1024
                                     + h * 64 + ct * 16 + quad * 4],
                    __ATOMIC_RELAXED, __HIP_MEMORY_SCOPE_AGENT);
                union { u64 u; ushort4 s; } cv; cv.u = pbits;
                const ushort4 pp = cv.s;
                const float r0 = (h2f(own[ct][nt].x) + h2f(pp.x)) * il[nt];
                const float r1 = (h2f(own[ct][nt].y) + h2f(pp.y)) * il[nt];
                const float r2 = (h2f(own[ct][nt].z) + h2f(pp.z)) * il[nt];
                const float r3 = (h2f(own[ct][nt].w) + h2f(pp.w)) * il[nt];
                uint2 ow;
                ow.x = (uint)f2bf(r0) | ((uint)f2bf(r1) << 16);
                ow.y = (uint)f2bf(r2) | ((uint)f2bf(r3) << 16);
                *(uint2*)&attb[((size_t)(qrow + nt * 16)) * 1024
                               + h * 64 + ct * 16 + quad * 4] = ow;
            }
    }
}

// ---------------------------------------------------------------------------
extern "C" void kernel_launch(void* const* d_in, const int* in_sizes, int n_in,
                              void* d_out, int out_size, void* d_ws, size_t ws_size,
                              hipStream_t stream) {
    const float* x    = (const float*)d_in[0];
    const float* Wqkv = (const float*)d_in[1];
    const float* bqkv = (const float*)d_in[2];
    const float* Wout = (const float*)d_in[3];
    const float* bout = (const float*)d_in[4];
    float* out = (float*)d_out;

    u16*   xb    = (u16*)d_ws;                               //  8 MB [4096][1024]
    u16*   WqT   = xb    + (size_t)4096 * 1024;              //  6 MB [3072][1024]
    u16*   WoT   = WqT   + (size_t)3072 * 1024;              //  2 MB [1024][1024]
    u16*   qkvb  = WoT   + (size_t)1024 * 1024;              // 16 MB [4096][2048] Q,K
    u16*   attb  = qkvb  + (size_t)4096 * 2048;              //  8 MB [4096][1024]
    u16*   vglob = attb  + (size_t)4096 * 1024;              //  8 MB [2][16][64][2048]
    u16*   wsO   = vglob + (size_t)4096 * 2048;              // 16 MB [2][4096][1024] fp16
    float* wsL   = (float*)(wsO + (size_t)2 * 4096 * 1024);  // 512 KB [2][16][4096]
    int*   cnt   = (int*)(wsL + (size_t)2 * Hh * 4096);      //   2 KB [512]

    prep<<<dim3(2048 + 768 + 256 + 1), dim3(256), 0, stream>>>(
        x, xb, Wqkv, WqT, Wout, WoT, cnt);

    gemm_bt<1><<<dim3(3072 / 128, 4096 / 128), dim3(256), 0, stream>>>(
        xb, WqT, bqkv, qkvb, vglob, 4096, 3072, 1024);

    attn_split<<<dim3(Hh * Bb, 32), dim3(256), 0, stream>>>(
        qkvb, vglob, wsO, wsL, attb, cnt);

    gemm_bt<0><<<dim3(1024 / 128, 4096 / 128), dim3(256), 0, stream>>>(
        attb, WoT, bout, out, nullptr, 4096, 1024, 1024);
}

// Round 12
// 183.660 us; speedup vs baseline: 1.2000x; 1.2000x over previous
//
#include <hip/hip_runtime.h>
#include <hip/hip_bf16.h>
#include <hip/hip_fp16.h>

typedef __attribute__((ext_vector_type(8))) short bf16x8;   // 8 bf16 = 4 VGPRs
typedef __attribute__((ext_vector_type(4))) float f32x4;
typedef unsigned short u16;
typedef unsigned int uint;
typedef unsigned long long u64;

#define Bb 2
#define Tt 2048
#define Dd 1024
#define Hh 16

#define EXP2F(x) __builtin_amdgcn_exp2f(x)

__device__ inline u16 f2bf(float f) {
    union { float f; uint u; } v; v.f = f;
    uint r = v.u + 0x7fffu + ((v.u >> 16) & 1u);   // RNE
    return (u16)(r >> 16);
}
__device__ inline uint fbits(float f) { union { float f; uint u; } v; v.f = f; return v.u; }
__device__ inline u16 f2h(float f) { return __half_as_ushort(__float2half(f)); }
__device__ inline float h2f(u16 u) { return __half2float(__ushort_as_half(u)); }

// async global->LDS, 16B per lane; dest wave-uniform base + lane*16.
__device__ inline void glds16(const u16* g, u16* l) {
    __builtin_amdgcn_global_load_lds(
        (const __attribute__((address_space(1))) void*)g,
        (__attribute__((address_space(3))) void*)l,
        16, 0, 0);
}

// ---------------------------------------------------------------------------
// prep: fused {fp32->bf16 cvt of x} + {transpose_cvt Wqkv} + {transpose_cvt
// Wout} + {zero split-K counters} in one dispatch. Role by blockIdx.x:
//   [0,2048)        cvt 8 elems/thread of x -> xb
//   [2048,2816)     Wqkv [1024][3072] -> WqT [3072][1024]
//   [2816,3072)     Wout [1024][1024] -> WoT [1024][1024]
//   3072            zero ALL 512 attn split-K arrival counters
// ---------------------------------------------------------------------------
__global__ __launch_bounds__(256) void prep(
    const float* __restrict__ x, u16* __restrict__ xb,
    const float* __restrict__ Wqkv, u16* __restrict__ WqT,
    const float* __restrict__ Wout, u16* __restrict__ WoT,
    int* __restrict__ cnt)
{
    __shared__ float tile[64][65];
    const int bid = blockIdx.x;
    const int tid = threadIdx.x;

    if (bid == 3072) {           // counter-zero role: 256 threads x 2 entries
        cnt[tid]       = 0;
        cnt[tid + 256] = 0;
        return;
    }
    if (bid < 2048) {            // elementwise cvt role
        const size_t i = ((size_t)bid * 256 + tid) * 8;
        const float4 a = *(const float4*)&x[i];
        const float4 b = *(const float4*)&x[i + 4];
        uint4 o;
        o.x = (uint)f2bf(a.x) | ((uint)f2bf(a.y) << 16);
        o.y = (uint)f2bf(a.z) | ((uint)f2bf(a.w) << 16);
        o.z = (uint)f2bf(b.x) | ((uint)f2bf(b.y) << 16);
        o.w = (uint)f2bf(b.z) | ((uint)f2bf(b.w) << 16);
        *(uint4*)&xb[i] = o;
        return;
    }

    const float* W; u16* Wt; int N, bx, by;
    const int K = 1024;
    if (bid < 2048 + 768) {
        const int r = bid - 2048;
        W = Wqkv; Wt = WqT; N = 3072; bx = r % 48; by = r / 48;
    } else {
        const int r = bid - 2816;
        W = Wout; Wt = WoT; N = 1024; bx = r & 15; by = r >> 4;
    }
    const int k0 = by * 64, n0 = bx * 64;
    const int tr = tid >> 4;
    const int tc = (tid & 15) * 4;

    #pragma unroll
    for (int i = 0; i < 4; ++i) {
        const float4 v = *(const float4*)&W[(size_t)(k0 + tr + i * 16) * N + n0 + tc];
        tile[tr + i * 16][tc + 0] = v.x;
        tile[tr + i * 16][tc + 1] = v.y;
        tile[tr + i * 16][tc + 2] = v.z;
        tile[tr + i * 16][tc + 3] = v.w;
    }
    __syncthreads();
    #pragma unroll
    for (int i = 0; i < 4; ++i) {
        ushort4 o;
        o.x = f2bf(tile[tc + 0][tr + i * 16]);
        o.y = f2bf(tile[tc + 1][tr + i * 16]);
        o.z = f2bf(tile[tc + 2][tr + i * 16]);
        o.w = f2bf(tile[tc + 3][tr + i * 16]);
        *(ushort4*)&Wt[(size_t)(n0 + tr + i * 16) * K + k0 + tc] = o;
    }
}

// ---------------------------------------------------------------------------
// C = A @ Bt^T + bias, bf16 MFMA. m97-style glds staging + double-buffered
// prefetch (one barrier per K-iter). 2x16 KB LDS. XOR source swizzle,
// conflict-free frag reads. VERIFIED 45 µs structure.
// MODE 0: fp32 out, row-major stride N (gemm2).
// MODE 1: qkv proj: cols <2048 -> bf16 qkvb stride 2048 (Q,K);
//         cols >=2048 -> V scattered transposed into vg[b][h][d][T].
// ---------------------------------------------------------------------------
template <int MODE>
__global__ __launch_bounds__(256) void gemm_bt(
    const u16* __restrict__ A, const u16* __restrict__ Bt,
    const float* __restrict__ bias, void* __restrict__ C,
    u16* __restrict__ vg, int M, int N, int K)
{
    __shared__ u16 As[2][128 * 32];
    __shared__ u16 Bs[2][128 * 32];

    const int tid  = threadIdx.x;
    const int lane = tid & 63;
    const int w    = tid >> 6;
    const int wm   = w >> 1, wn = w & 1;
    const int quad = lane >> 4;
    const int m16  = lane & 15;
    const int row0 = blockIdx.y * 128;
    const int col0 = blockIdx.x * 128;

    f32x4 acc[4][4];
    #pragma unroll
    for (int i = 0; i < 4; ++i)
        #pragma unroll
        for (int j = 0; j < 4; ++j) acc[i][j] = (f32x4){0.f, 0.f, 0.f, 0.f};

    const int sr  = tid >> 2, sqs = tid & 3;
    const int sq  = sqs ^ ((sr >> 1) & 3);
    const int ldsw = w * 512;
    const int slot = quad ^ ((m16 >> 1) & 3);

    const int nIter = K >> 5;

    // prologue: stage iter 0 into buf 0
    glds16(&A [(size_t)(row0 + sr) * K + sq * 8],       &As[0][ldsw]);
    glds16(&A [(size_t)(row0 + sr + 64) * K + sq * 8],  &As[0][2048 + ldsw]);
    glds16(&Bt[(size_t)(col0 + sr) * K + sq * 8],       &Bs[0][ldsw]);
    glds16(&Bt[(size_t)(col0 + sr + 64) * K + sq * 8],  &Bs[0][2048 + ldsw]);

    for (int it = 0; it < nIter; ++it) {
        const int cb = it & 1;
        __syncthreads();   // drains glds(iter it); all waves done reading buf cb^1

        if (it + 1 < nIter) {   // prefetch next k-slab into the other buffer
            const int ko = (it + 1) << 5;
            const int nb = cb ^ 1;
            glds16(&A [(size_t)(row0 + sr) * K + ko + sq * 8],       &As[nb][ldsw]);
            glds16(&A [(size_t)(row0 + sr + 64) * K + ko + sq * 8],  &As[nb][2048 + ldsw]);
            glds16(&Bt[(size_t)(col0 + sr) * K + ko + sq * 8],       &Bs[nb][ldsw]);
            glds16(&Bt[(size_t)(col0 + sr + 64) * K + ko + sq * 8],  &Bs[nb][2048 + ldsw]);
        }

        bf16x8 af[4], bfr[4];
        #pragma unroll
        for (int mt = 0; mt < 4; ++mt)
            af[mt] = *(const bf16x8*)&As[cb][(wm * 64 + mt * 16 + m16) * 32 + slot * 8];
        #pragma unroll
        for (int nt = 0; nt < 4; ++nt)
            bfr[nt] = *(const bf16x8*)&Bs[cb][(wn * 64 + nt * 16 + m16) * 32 + slot * 8];
        #pragma unroll
        for (int mt = 0; mt < 4; ++mt)
            #pragma unroll
            for (int nt = 0; nt < 4; ++nt)
                acc[mt][nt] = __builtin_amdgcn_mfma_f32_16x16x32_bf16(
                    af[mt], bfr[nt], acc[mt][nt], 0, 0, 0);
    }

    #pragma unroll
    for (int mt = 0; mt < 4; ++mt) {
        #pragma unroll
        for (int nt = 0; nt < 4; ++nt) {
            const int row = row0 + wm * 64 + mt * 16 + quad * 4;
            const int col = col0 + wn * 64 + nt * 16 + m16;
            const float bv = bias[col];
            #pragma unroll
            for (int r = 0; r < 4; ++r) {
                const float v = acc[mt][nt][r] + bv;
                if (MODE == 0) {
                    ((float*)C)[(size_t)(row + r) * N + col] = v;
                } else {
                    if (col0 < 2048) {   // Q,K region (block never straddles)
                        ((u16*)C)[(size_t)(row + r) * 2048 + col] = f2bf(v);
                    } else {             // V: write transposed into vg[b][h][d][T]
                        const int hcol = col - 2048;
                        const int hh = hcol >> 6, dd = hcol & 63;
                        const int bb = (row + r) >> 11, tt = (row + r) & 2047;
                        vg[((size_t)(bb * Hh + hh) * 64 + dd) * Tt + tt] = f2bf(v);
                    }
                }
            }
        }
    }
}

// ---------------------------------------------------------------------------
// Flash causal attention v9 (R18 config, RESTORED): KV double-buffered with
// the verified gemm_bt sync pattern (one __syncthreads per K-tile; prefetch
// t+2 under the compute phase). Pt LDS bounce RETAINED — R19's in-register
// shuffle redistribute regressed 44.9->80.5 us (scratch spills: WRITE_SIZE
// 25->73 MB; ds_bpermute = LDS op, conflicts 1.6M->2.97M).
// Split-K(2) + fixed-offset softmax + T5 setprio + sc1 fused combine
// (R15-verified: no fences — __threadfence costs +200 us via L2 flush).
// ---------------------------------------------------------------------------
__global__ __launch_bounds__(256, 3) void attn_split(
    const u16* __restrict__ qkvb, const u16* __restrict__ vglob,
    u16* __restrict__ wsO, float* __restrict__ wsL,
    u16* __restrict__ attb, int* __restrict__ cnt)
{
    const int hb  = blockIdx.x;
    const int h   = hb & 15, b = hb >> 4;
    const int qt  = 15 - (blockIdx.y >> 1);   // heavy-first
    const int half = blockIdx.y & 1;
    const int tid = threadIdx.x;
    const int lane = tid & 63, w = tid >> 6;
    const int quad = lane >> 4, m16 = lane & 15;

    __shared__ u16 KV[2][2][64 * 64];    // [buf][K=0/Vt=1], 32 KB
    __shared__ u16 Pt[128 * 72];         // 18 KB
    __shared__ int sflag;

    const int q0 = qt * 128;
    const size_t qkbase = (size_t)(b * Tt) * 2048;
    const size_t vbase  = (size_t)((b * Hh + h) * 64) * Tt;

    const int sr8 = tid >> 3;                // 0..31
    const int sq8 = (tid & 7) ^ (sr8 & 7);
    const int ldsw = w * 512;
    const int slot = quad ^ (m16 & 7);       // ks=0 read slot; ks=1 -> ^4

    // Q^T B-frags, loop-invariant, from global:
    bf16x8 qb[2][2];
    #pragma unroll
    for (int nt = 0; nt < 2; ++nt)
        #pragma unroll
        for (int ks = 0; ks < 2; ++ks)
            qb[nt][ks] = *(const bf16x8*)&qkvb[
                qkbase + (size_t)(q0 + w * 32 + nt * 16 + m16) * 2048
                + h * 64 + ks * 32 + quad * 8];

    f32x4 o[4][2];
    #pragma unroll
    for (int ct = 0; ct < 4; ++ct)
        #pragma unroll
        for (int nt = 0; nt < 2; ++nt) o[ct][nt] = (f32x4){0.f, 0.f, 0.f, 0.f};
    float ls[2] = {0.f, 0.f};
    const float sc2 = 0.125f * 1.4426950408889634f;   // scale*log2(e)

    #define STAGE_KV(K0, BUF) do {                                             \
        _Pragma("unroll")                                                      \
        for (int j_ = 0; j_ < 2; ++j_) {                                       \
            const int row_ = j_ * 32 + sr8;                                    \
            glds16(&qkvb[qkbase + (size_t)((K0) + row_) * 2048 + 1024          \
                         + h * 64 + sq8 * 8],                                  \
                   &KV[BUF][0][j_ * 2048 + ldsw]);                             \
            glds16(&vglob[vbase + (size_t)row_ * Tt + (K0) + sq8 * 8],         \
                   &KV[BUF][1][j_ * 2048 + ldsw]);                             \
        }                                                                      \
    } while (0)

    const int ntiles = 2 * qt + 2;
    // prologue: stage first tile into buf 0
    STAGE_KV(half * 64, 0);

    int it = 0;
    for (int kt = half; kt < ntiles; kt += 2, ++it) {
        const int k0 = kt * 64;
        const int cb = it & 1;
        __syncthreads();   // vmcnt(0)+barrier: buf cb visible; reads of cb^1 retired

        if (kt + 2 < ntiles)            // prefetch tile t+2 into the other buffer
            STAGE_KV((kt + 2) * 64, cb ^ 1);

        if (k0 <= q0 + w * 32 + 31) {    // wave-uniform visibility
            const u16* Ks = KV[cb][0];
            const u16* Vt = KV[cb][1];

            // S^T = K · Q^T
            bf16x8 ak[4][2];
            #pragma unroll
            for (int mt = 0; mt < 4; ++mt) {
                const int ro = (mt * 16 + m16) * 64;
                ak[mt][0] = *(const bf16x8*)&Ks[ro + slot * 8];
                ak[mt][1] = *(const bf16x8*)&Ks[ro + (slot ^ 4) * 8];
            }
            f32x4 s[4][2];
            __builtin_amdgcn_s_setprio(1);
            #pragma unroll
            for (int mt = 0; mt < 4; ++mt)
                #pragma unroll
                for (int nt = 0; nt < 2; ++nt) {
                    f32x4 a = (f32x4){0.f, 0.f, 0.f, 0.f};
                    a = __builtin_amdgcn_mfma_f32_16x16x32_bf16(ak[mt][0], qb[nt][0], a, 0, 0, 0);
                    a = __builtin_amdgcn_mfma_f32_16x16x32_bf16(ak[mt][1], qb[nt][1], a, 0, 0, 0);
                    s[mt][nt] = a;
                }
            __builtin_amdgcn_s_setprio(0);

            // p = exp2(s*sc2 - 8), causal mask -> 0; accumulate l per-lane.
            const int qi0 = q0 + w * 32 + m16;
            const bool diag = (k0 + 63 > q0 + w * 32);
            #pragma unroll
            for (int mt = 0; mt < 4; ++mt)
                #pragma unroll
                for (int nt = 0; nt < 2; ++nt) {
                    float p[4];
                    const int kb = k0 + mt * 16 + quad * 4;
                    #pragma unroll
                    for (int r = 0; r < 4; ++r) {
                        float t = __builtin_fmaf(s[mt][nt][r], sc2, -8.0f);
                        if (diag) t = (kb + r <= qi0 + nt * 16) ? t : -1000.0f;
                        p[r] = EXP2F(t);
                    }
                    ls[nt] += (p[0] + p[1]) + (p[2] + p[3]);
                    uint2 pk;   // truncation-pack to bf16 pairs
                    pk.x = (fbits(p[0]) >> 16) | (fbits(p[1]) & 0xffff0000u);
                    pk.y = (fbits(p[2]) >> 16) | (fbits(p[3]) & 0xffff0000u);
                    *(uint2*)&Pt[(w * 32 + nt * 16 + m16) * 72 + mt * 16 + quad * 4] = pk;
                }

            // O^T += V^T · P^T  (same-wave Pt write->read)
            bf16x8 av[4][2], pb[2][2];
            #pragma unroll
            for (int ct = 0; ct < 4; ++ct) {
                const int ro = (ct * 16 + m16) * 64;
                av[ct][0] = *(const bf16x8*)&Vt[ro + slot * 8];
                av[ct][1] = *(const bf16x8*)&Vt[ro + (slot ^ 4) * 8];
            }
            #pragma unroll
            for (int nt = 0; nt < 2; ++nt)
                #pragma unroll
                for (int ks = 0; ks < 2; ++ks)
                    pb[nt][ks] = *(const bf16x8*)&Pt[(w * 32 + nt * 16 + m16) * 72 + ks * 32 + quad * 8];
            __builtin_amdgcn_s_setprio(1);
            #pragma unroll
            for (int ct = 0; ct < 4; ++ct)
                #pragma unroll
                for (int nt = 0; nt < 2; ++nt) {
                    o[ct][nt] = __builtin_amdgcn_mfma_f32_16x16x32_bf16(av[ct][0], pb[nt][0], o[ct][nt], 0, 0, 0);
                    o[ct][nt] = __builtin_amdgcn_mfma_f32_16x16x32_bf16(av[ct][1], pb[nt][1], o[ct][nt], 0, 0, 0);
                }
            __builtin_amdgcn_s_setprio(0);
        }
    }
    #undef STAGE_KV

    // epilogue: reduce l across quads (all lanes end with the full sum).
    #pragma unroll
    for (int nt = 0; nt < 2; ++nt) {
        ls[nt] += __shfl_xor(ls[nt], 16);
        ls[nt] += __shfl_xor(ls[nt], 32);
    }
    const int qrow = b * Tt + q0 + w * 32 + m16;
    if (quad == 0) {
        __hip_atomic_store(&wsL[(half * Hh + h) * 4096 + qrow], ls[0],
                           __ATOMIC_RELAXED, __HIP_MEMORY_SCOPE_AGENT);
        __hip_atomic_store(&wsL[(half * Hh + h) * 4096 + qrow + 16], ls[1],
                           __ATOMIC_RELAXED, __HIP_MEMORY_SCOPE_AGENT);
    }
    // own fp16 partial: agent-scope (sc1) stores, device-visible at vmcnt retire
    ushort4 own[4][2];
    #pragma unroll
    for (int ct = 0; ct < 4; ++ct)
        #pragma unroll
        for (int nt = 0; nt < 2; ++nt) {
            ushort4 pk;
            pk.x = f2h(o[ct][nt][0]);
            pk.y = f2h(o[ct][nt][1]);
            pk.z = f2h(o[ct][nt][2]);
            pk.w = f2h(o[ct][nt][3]);
            own[ct][nt] = pk;
            union { ushort4 s; u64 u; } cv; cv.s = pk;
            __hip_atomic_store(
                (u64*)&wsO[((size_t)(half * 4096 + qrow + nt * 16)) * 1024
                           + h * 64 + ct * 16 + quad * 4],
                cv.u, __ATOMIC_RELAXED, __HIP_MEMORY_SCOPE_AGENT);
        }

    // last-arrival combine: syncthreads (vmcnt0 -> all sc1 stores device-
    // visible) -> ticket -> combiner reads partner with agent loads.
    __syncthreads();
    if (tid == 0) sflag = atomicAdd(&cnt[hb * 16 + qt], 1);
    __syncthreads();
    if (sflag == 1) {
        const int oh = half ^ 1;
        const float lo0 = __hip_atomic_load(&wsL[(oh * Hh + h) * 4096 + qrow],
                                            __ATOMIC_RELAXED, __HIP_MEMORY_SCOPE_AGENT);
        const float lo1 = __hip_atomic_load(&wsL[(oh * Hh + h) * 4096 + qrow + 16],
                                            __ATOMIC_RELAXED, __HIP_MEMORY_SCOPE_AGENT);
        const float il[2] = { 1.0f / (ls[0] + lo0), 1.0f / (ls[1] + lo1) };
        #pragma unroll
        for (int ct = 0; ct < 4; ++ct)
            #pragma unroll
            for (int nt = 0; nt < 2; ++nt) {
                const u64 pbits = __hip_atomic_load(
                    (const u64*)&wsO[((size_t)(oh * 4096 + qrow + nt * 16)) * 1024
                                     + h * 64 + ct * 16 + quad * 4],
                    __ATOMIC_RELAXED, __HIP_MEMORY_SCOPE_AGENT);
                union { u64 u; ushort4 s; } cv; cv.u = pbits;
                const ushort4 pp = cv.s;
                const float r0 = (h2f(own[ct][nt].x) + h2f(pp.x)) * il[nt];
                const float r1 = (h2f(own[ct][nt].y) + h2f(pp.y)) * il[nt];
                const float r2 = (h2f(own[ct][nt].z) + h2f(pp.z)) * il[nt];
                const float r3 = (h2f(own[ct][nt].w) + h2f(pp.w)) * il[nt];
                uint2 ow;
                ow.x = (uint)f2bf(r0) | ((uint)f2bf(r1) << 16);
                ow.y = (uint)f2bf(r2) | ((uint)f2bf(r3) << 16);
                *(uint2*)&attb[((size_t)(qrow + nt * 16)) * 1024
                               + h * 64 + ct * 16 + quad * 4] = ow;
            }
    }
}

// ---------------------------------------------------------------------------
extern "C" void kernel_launch(void* const* d_in, const int* in_sizes, int n_in,
                              void* d_out, int out_size, void* d_ws, size_t ws_size,
                              hipStream_t stream) {
    const float* x    = (const float*)d_in[0];
    const float* Wqkv = (const float*)d_in[1];
    const float* bqkv = (const float*)d_in[2];
    const float* Wout = (const float*)d_in[3];
    const float* bout = (const float*)d_in[4];
    float* out = (float*)d_out;

    u16*   xb    = (u16*)d_ws;                               //  8 MB [4096][1024]
    u16*   WqT   = xb    + (size_t)4096 * 1024;              //  6 MB [3072][1024]
    u16*   WoT   = WqT   + (size_t)3072 * 1024;              //  2 MB [1024][1024]
    u16*   qkvb  = WoT   + (size_t)1024 * 1024;              // 16 MB [4096][2048] Q,K
    u16*   attb  = qkvb  + (size_t)4096 * 2048;              //  8 MB [4096][1024]
    u16*   vglob = attb  + (size_t)4096 * 1024;              //  8 MB [2][16][64][2048]
    u16*   wsO   = vglob + (size_t)4096 * 2048;              // 16 MB [2][4096][1024] fp16
    float* wsL   = (float*)(wsO + (size_t)2 * 4096 * 1024);  // 512 KB [2][16][4096]
    int*   cnt   = (int*)(wsL + (size_t)2 * Hh * 4096);      //   2 KB [512]

    prep<<<dim3(2048 + 768 + 256 + 1), dim3(256), 0, stream>>>(
        x, xb, Wqkv, WqT, Wout, WoT, cnt);

    gemm_bt<1><<<dim3(3072 / 128, 4096 / 128), dim3(256), 0, stream>>>(
        xb, WqT, bqkv, qkvb, vglob, 4096, 3072, 1024);

    attn_split<<<dim3(Hh * Bb, 32), dim3(256), 0, stream>>>(
        qkvb, vglob, wsO, wsL, attb, cnt);

    gemm_bt<0><<<dim3(1024 / 128, 4096 / 128), dim3(256), 0, stream>>>(
        attb, WoT, bout, out, nullptr, 4096, 1024, 1024);
}